// Round 3
// baseline (386.768 us; speedup 1.0000x reference)
//
#include <hip/hip_runtime.h>
#include <hip/hip_bf16.h>

typedef __attribute__((ext_vector_type(8))) short short8;
typedef __attribute__((ext_vector_type(4))) float f32x4;

#define GLOBAL_AS __attribute__((address_space(1)))
#define LDS_AS    __attribute__((address_space(3)))

__device__ __forceinline__ void async_ld16(const void* g, void* l) {
    __builtin_amdgcn_global_load_lds((const GLOBAL_AS void*)g, (LDS_AS void*)l, 16, 0, 0);
}

__device__ __forceinline__ unsigned short f2bf(float x) {
    union { __hip_bfloat16 h; unsigned short u; } cv;
    cv.h = __float2bfloat16(x);
    return cv.u;
}

// One block per row (D=1024: 256 threads x float4). Rows >= rows_in write zeros.
__global__ __launch_bounds__(256) void norm_rows_kernel(
    const float* __restrict__ in, unsigned short* __restrict__ outb, int rows_in)
{
    const int row = blockIdx.x;
    const int tid = threadIdx.x;
    float4 v = make_float4(0.f, 0.f, 0.f, 0.f);
    if (row < rows_in)
        v = reinterpret_cast<const float4*>(in + (size_t)row * 1024)[tid];
    float s = v.x * v.x + v.y * v.y + v.z * v.z + v.w * v.w;
    #pragma unroll
    for (int off = 32; off > 0; off >>= 1) s += __shfl_down(s, off);
    __shared__ float sr[4];
    if ((tid & 63) == 0) sr[tid >> 6] = s;
    __syncthreads();
    const float tot = sr[0] + sr[1] + sr[2] + sr[3];
    const float inv = 1.f / fmaxf(sqrtf(tot), 1e-12f);
    ushort4 o;
    o.x = f2bf(v.x * inv);
    o.y = f2bf(v.y * inv);
    o.z = f2bf(v.z * inv);
    o.w = f2bf(v.w * inv);
    reinterpret_cast<ushort4*>(outb + (size_t)row * 1024)[tid] = o;
}

__global__ __launch_bounds__(256) void zero_f32_kernel(float* __restrict__ p, int n)
{
    const int i = blockIdx.x * 256 + threadIdx.x;
    if (i < n) p[i] = 0.f;
}

// 256x256 tile, BK=64, 8 waves (2Mx4N), 16x16x32 bf16 MFMA, 8x4 frags/wave.
// Double-buffered LDS (2 x 64KB), 2-deep prefetch, counted vmcnt(8) (T3/T4),
// T2 source-side XOR swizzle, T5 setprio, T1 XCD swizzle.
// Epilogue: iso = |ds|*sqrt(max(2-2dot,eps))/sqrt2, store + per-row atomic sum.
__global__ __launch_bounds__(512, 2) void gemm_iso_kernel(
    const unsigned short* __restrict__ A,   // [M][1024] bf16 normalized features
    const unsigned short* __restrict__ B,   // [Npad][1024] bf16 normalized prototypes
    float* __restrict__ out,                // [M][C] iso
    float* __restrict__ rowsum,             // [M] zero-initialized
    const float* __restrict__ ds_ptr,
    int M, int C, int K)
{
    __shared__ __align__(16) char lds[131072];   // buf0: A 32K | B 32K ; buf1: same

    const float dsv_raw = ds_ptr[0];   // oldest vmem op: drained by prologue vmcnt

    const int tid  = threadIdx.x;
    const int lane = tid & 63;
    const int wid  = tid >> 6;

    // T1: XCD-bijective swizzle (nwg = 640, divisible by 8)
    const int nwg  = gridDim.x * gridDim.y;
    const int orig = blockIdx.y * gridDim.x + blockIdx.x;
    const int cpx  = nwg >> 3;
    const int swz  = (orig & 7) * cpx + (orig >> 3);
    const int bx   = swz % gridDim.x;
    const int by   = swz / gridDim.x;
    const int brow = by * 256;
    const int bcol = bx * 256;

    // ---- staging: per operand 32KB = 32 wave-loads; wave w owns segs w*4..w*4+3
    const int lrow8 = lane >> 3;             // row within 8-row seg
    const int slotg = (lane & 7) ^ lrow8;    // pre-swizzled 16B slot (T2 write side)
    const size_t kb = (size_t)K * 2;

    const char* pA[4]; const char* pB[4]; int lA[4], lB[4];
    #pragma unroll
    for (int i = 0; i < 4; ++i) {
        const int seg = wid * 4 + i;         // 0..31
        const int r   = seg * 8 + lrow8;     // 0..255
        pA[i] = (const char*)A + (size_t)(brow + r) * kb + slotg * 16;
        pB[i] = (const char*)B + (size_t)(bcol + r) * kb + slotg * 16;
        lA[i] = seg * 1024;                  // wave-uniform LDS dests (SGPR)
        lB[i] = 32768 + seg * 1024;
    }

    auto STAGE = [&](int buf) {              // 8 loads; advances pointers by BK
        char* base = lds + (buf << 16);
        #pragma unroll
        for (int i = 0; i < 4; ++i) async_ld16(pA[i], base + lA[i]);
        #pragma unroll
        for (int i = 0; i < 4; ++i) async_ld16(pB[i], base + lB[i]);
        #pragma unroll
        for (int i = 0; i < 4; ++i) { pA[i] += 128; pB[i] += 128; }
    };

    // ---- compute mapping: wave (wid>>2, wid&3) owns 128x64 of the 256x256 tile
    const int wr = (wid >> 2) * 128;
    const int wc = (wid & 3) * 64;
    const int lr = lane & 15;
    const int kq = lane >> 4;
    const int sx = lr & 7;                   // T2 read-side XOR (row&7)

    f32x4 acc[8][4];
    #pragma unroll
    for (int m = 0; m < 8; ++m)
        #pragma unroll
        for (int n = 0; n < 4; ++n)
            acc[m][n] = (f32x4){0.f, 0.f, 0.f, 0.f};

    int aoff[8], boff[4];
    #pragma unroll
    for (int m = 0; m < 8; ++m) aoff[m] = (wr + m * 16 + lr) * 128;
    #pragma unroll
    for (int n = 0; n < 4; ++n) boff[n] = 32768 + (wc + n * 16 + lr) * 128;
    const int so0 = ((0 + kq) ^ sx) * 16;    // kk=0 slots
    const int so1 = ((4 + kq) ^ sx) * 16;    // kk=1 slots

    auto COMPUTE = [&](int buf) {
        const char* base = lds + (buf << 16);
        #pragma unroll
        for (int kk = 0; kk < 2; ++kk) {
            const int so = kk ? so1 : so0;
            short8 a[8], b[4];
            #pragma unroll
            for (int m = 0; m < 8; ++m)
                a[m] = *reinterpret_cast<const short8*>(base + aoff[m] + so);
            #pragma unroll
            for (int n = 0; n < 4; ++n)
                b[n] = *reinterpret_cast<const short8*>(base + boff[n] + so);
            __builtin_amdgcn_s_setprio(1);
            #pragma unroll
            for (int m = 0; m < 8; ++m)
                #pragma unroll
                for (int n = 0; n < 4; ++n)
                    acc[m][n] = __builtin_amdgcn_mfma_f32_16x16x32_bf16(
                        a[m], b[n], acc[m][n], 0, 0, 0);
            __builtin_amdgcn_s_setprio(0);
        }
    };

    // ---- pipelined K-loop: 2 tiles in flight, vmcnt never drained to 0 mid-loop
    const int nt = K >> 6;                   // 16
    STAGE(0);
    STAGE(1);
    asm volatile("s_waitcnt vmcnt(8)" ::: "memory");   // tile0 landed
    __builtin_amdgcn_s_barrier();
    __builtin_amdgcn_sched_barrier(0);

    for (int t = 0; t < nt; ++t) {
        COMPUTE(t & 1);
        if (t + 1 < nt) {
            __builtin_amdgcn_s_barrier();              // all waves done reading buf
            __builtin_amdgcn_sched_barrier(0);
            if (t + 2 < nt) {
                STAGE(t & 1);                          // tile t+2 into freed buf
                asm volatile("s_waitcnt vmcnt(8)" ::: "memory");  // tile t+1 landed
            } else {
                asm volatile("s_waitcnt vmcnt(0)" ::: "memory");
            }
            __builtin_amdgcn_s_barrier();
            __builtin_amdgcn_sched_barrier(0);
        }
    }

    // ---- epilogue: iso, store, fused row-sum (padded cols masked)
    const float dsv = fabsf(dsv_raw);
    #pragma unroll
    for (int m = 0; m < 8; ++m) {
        float rs0 = 0.f, rs1 = 0.f, rs2 = 0.f, rs3 = 0.f;
        const int row0 = brow + wr + m * 16 + kq * 4;   // C/D: row=(lane>>4)*4+j
        #pragma unroll
        for (int n = 0; n < 4; ++n) {
            const int col = bcol + wc + n * 16 + lr;    // col = lane&15
            const bool ok = col < C;
            float* op = out + (size_t)row0 * C + col;
            #pragma unroll
            for (int j = 0; j < 4; ++j) {
                const float sq  = fmaxf(2.f - 2.f * acc[m][n][j], 1e-12f);
                const float iso = dsv * (sqrtf(sq) * 0.70710678118654752f);
                if (ok) op[(size_t)j * C] = iso;
                const float c = ok ? iso : 0.f;
                if (j == 0) rs0 += c; else if (j == 1) rs1 += c;
                else if (j == 2) rs2 += c; else rs3 += c;
            }
        }
        float r4[4] = {rs0, rs1, rs2, rs3};
        #pragma unroll
        for (int j = 0; j < 4; ++j) {
            float r = r4[j];
            r += __shfl_xor(r, 1);
            r += __shfl_xor(r, 2);
            r += __shfl_xor(r, 4);
            r += __shfl_xor(r, 8);           // 16-lane group = full 64-col span
            if (lr == 0) atomicAdd(&rowsum[row0 + j], r);
        }
    }
}

// Pure streaming: logits = -(iso + rowsum/C) / T. One float4 per thread.
__global__ __launch_bounds__(256) void finalize_kernel(
    float* __restrict__ out, const float* __restrict__ rowsum,
    const float* __restrict__ tptr, int C)
{
    const int row = blockIdx.y;
    const int i4  = blockIdx.x * 256 + threadIdx.x;
    const int n4  = C >> 2;                   // C % 4 == 0 (10000)
    if (i4 >= n4) return;
    const float mean = rowsum[row] / (float)C;
    const float invT = 1.f / tptr[0];
    float* rp = out + (size_t)row * C;
    float4 v = reinterpret_cast<const float4*>(rp)[i4];
    v.x = -(v.x + mean) * invT;
    v.y = -(v.y + mean) * invT;
    v.z = -(v.z + mean) * invT;
    v.w = -(v.w + mean) * invT;
    reinterpret_cast<float4*>(rp)[i4] = v;
}

extern "C" void kernel_launch(void* const* d_in, const int* in_sizes, int n_in,
                              void* d_out, int out_size, void* d_ws, size_t ws_size,
                              hipStream_t stream)
{
    const float* feat = (const float*)d_in[0];
    const float* prot = (const float*)d_in[1];
    const float* dsc  = (const float*)d_in[2];
    const float* temp = (const float*)d_in[3];
    float* out = (float*)d_out;

    const int D = 1024;
    const int M = in_sizes[0] / D;            // 4096
    const int C = in_sizes[1] / D;            // 10000
    const int NT = (C + 255) / 256;           // 40
    const int Npad = NT * 256;                // 10240

    // ws: rowsum [M] f32 | features bf16 [M][D] | prototypes bf16 [Npad][D]
    float* rowsum = (float*)d_ws;
    unsigned short* fbf = (unsigned short*)(rowsum + M);
    unsigned short* pbf = fbf + (size_t)M * D;

    norm_rows_kernel<<<M, 256, 0, stream>>>(feat, fbf, M);
    norm_rows_kernel<<<Npad, 256, 0, stream>>>(prot, pbf, C);
    zero_f32_kernel<<<(M + 255) / 256, 256, 0, stream>>>(rowsum, M);
    gemm_iso_kernel<<<dim3(NT, M / 256), 512, 0, stream>>>(fbf, pbf, out, rowsum, dsc, M, C, D);
    finalize_kernel<<<dim3((C / 4 + 255) / 256, M), 256, 0, stream>>>(out, rowsum, temp, C);
}

// Round 6
// 378.597 us; speedup vs baseline: 1.0216x; 1.0216x over previous
//
#include <hip/hip_runtime.h>
#include <hip/hip_bf16.h>

typedef __attribute__((ext_vector_type(8))) short short8;
typedef __attribute__((ext_vector_type(4))) float f32x4;

#define GLOBAL_AS __attribute__((address_space(1)))
#define LDS_AS    __attribute__((address_space(3)))

__device__ __forceinline__ void async_ld16(const void* g, void* l) {
    __builtin_amdgcn_global_load_lds((const GLOBAL_AS void*)g, (LDS_AS void*)l, 16, 0, 0);
}

__device__ __forceinline__ unsigned short f2bf(float x) {
    union { __hip_bfloat16 h; unsigned short u; } cv;
    cv.h = __float2bfloat16(x);
    return cv.u;
}

// One block per row (D=1024: 256 threads x float4). Rows >= rows_in write zeros.
// If rowsum != nullptr, thread 0 also zeroes rowsum[row] (fused zero_f32).
__global__ __launch_bounds__(256) void norm_rows_kernel(
    const float* __restrict__ in, unsigned short* __restrict__ outb, int rows_in,
    float* __restrict__ rowsum)
{
    const int row = blockIdx.x;
    const int tid = threadIdx.x;
    if (rowsum != nullptr && tid == 0) rowsum[row] = 0.f;
    float4 v = make_float4(0.f, 0.f, 0.f, 0.f);
    if (row < rows_in)
        v = reinterpret_cast<const float4*>(in + (size_t)row * 1024)[tid];
    float s = v.x * v.x + v.y * v.y + v.z * v.z + v.w * v.w;
    #pragma unroll
    for (int off = 32; off > 0; off >>= 1) s += __shfl_down(s, off);
    __shared__ float sr[4];
    if ((tid & 63) == 0) sr[tid >> 6] = s;
    __syncthreads();
    const float tot = sr[0] + sr[1] + sr[2] + sr[3];
    const float inv = 1.f / fmaxf(sqrtf(tot), 1e-12f);
    ushort4 o;
    o.x = f2bf(v.x * inv);
    o.y = f2bf(v.y * inv);
    o.z = f2bf(v.z * inv);
    o.w = f2bf(v.w * inv);
    reinterpret_cast<ushort4*>(outb + (size_t)row * 1024)[tid] = o;
}

// 256x256 tile, BK=64, 8 waves (2Mx4N), 16x16x32 bf16 MFMA, 8x4 frags/wave.
// T3+T4 "minimum 2-phase" recipe: STAGE(t+1) issued BEFORE compute(t);
// ONE vmcnt(0)+barrier per K-tile (drain hidden under the 64-MFMA stream).
// T2 source-side XOR swizzle (write) + matching read XOR. T5 setprio.
// T1 bijective XCD swizzle. Epilogue: iso + fused per-row atomic sum.
__global__ __launch_bounds__(512, 2) void gemm_iso_kernel(
    const unsigned short* __restrict__ A,   // [M][1024] bf16 normalized features
    const unsigned short* __restrict__ B,   // [Npad][1024] bf16 normalized prototypes
    float* __restrict__ out,                // [M][C] iso
    float* __restrict__ rowsum,             // [M] zero-initialized
    const float* __restrict__ ds_ptr,
    int M, int C, int K)
{
    __shared__ __align__(16) char lds[131072];   // buf0 | buf1, each A 32K + B 32K

    const float dsv_raw = ds_ptr[0];   // drained by prologue vmcnt(0)

    const int tid  = threadIdx.x;
    const int lane = tid & 63;
    const int wid  = tid >> 6;

    // T1: XCD-bijective swizzle (nwg = 640, divisible by 8)
    const int orig = blockIdx.y * gridDim.x + blockIdx.x;
    const int cpx  = (gridDim.x * gridDim.y) >> 3;
    const int swz  = (orig & 7) * cpx + (orig >> 3);
    const int bx   = swz % gridDim.x;
    const int by   = swz / gridDim.x;
    const int brow = by * 256;
    const int bcol = bx * 256;

    // ---- staging: per operand 32KB = 32 wave-loads; wave w owns segs w*4..w*4+3
    const int lrow8 = lane >> 3;             // row within 8-row seg
    const int slotg = (lane & 7) ^ lrow8;    // pre-swizzled 16B slot (T2 write side)
    const size_t kb = (size_t)K * 2;

    const char* pA[4]; const char* pB[4]; int lA[4], lB[4];
    #pragma unroll
    for (int i = 0; i < 4; ++i) {
        const int seg = wid * 4 + i;         // 0..31
        const int r   = seg * 8 + lrow8;     // 0..255
        pA[i] = (const char*)A + (size_t)(brow + r) * kb + slotg * 16;
        pB[i] = (const char*)B + (size_t)(bcol + r) * kb + slotg * 16;
        lA[i] = seg * 1024;                  // wave-uniform LDS dests
        lB[i] = 32768 + seg * 1024;
    }

    auto STAGE = [&](int buf) {              // 8 loads/thread-wave; advances by BK
        char* base = lds + (buf << 16);
        #pragma unroll
        for (int i = 0; i < 4; ++i) async_ld16(pA[i], base + lA[i]);
        #pragma unroll
        for (int i = 0; i < 4; ++i) async_ld16(pB[i], base + lB[i]);
        #pragma unroll
        for (int i = 0; i < 4; ++i) { pA[i] += 128; pB[i] += 128; }
    };

    // ---- compute mapping: wave (wid>>2, wid&3) owns 128x64 of the 256x256 tile
    const int wr = (wid >> 2) * 128;
    const int wc = (wid & 3) * 64;
    const int lr = lane & 15;
    const int kq = lane >> 4;
    const int sx = lr & 7;                   // T2 read-side XOR (row&7)

    f32x4 acc[8][4];
    #pragma unroll
    for (int m = 0; m < 8; ++m)
        #pragma unroll
        for (int n = 0; n < 4; ++n)
            acc[m][n] = (f32x4){0.f, 0.f, 0.f, 0.f};

    int aoff[8], boff[4];
    #pragma unroll
    for (int m = 0; m < 8; ++m) aoff[m] = (wr + m * 16 + lr) * 128;
    #pragma unroll
    for (int n = 0; n < 4; ++n) boff[n] = 32768 + (wc + n * 16 + lr) * 128;
    const int so0 = ((0 + kq) ^ sx) * 16;    // kk=0 slots
    const int so1 = ((4 + kq) ^ sx) * 16;    // kk=1 slots

    auto COMPUTE = [&](int buf) {
        const char* base = lds + (buf << 16);
        #pragma unroll
        for (int kk = 0; kk < 2; ++kk) {
            const int so = kk ? so1 : so0;
            short8 a[8], b[4];
            #pragma unroll
            for (int m = 0; m < 8; ++m)
                a[m] = *reinterpret_cast<const short8*>(base + aoff[m] + so);
            #pragma unroll
            for (int n = 0; n < 4; ++n)
                b[n] = *reinterpret_cast<const short8*>(base + boff[n] + so);
            __builtin_amdgcn_s_setprio(1);
            #pragma unroll
            for (int m = 0; m < 8; ++m)
                #pragma unroll
                for (int n = 0; n < 4; ++n)
                    acc[m][n] = __builtin_amdgcn_mfma_f32_16x16x32_bf16(
                        a[m], b[n], acc[m][n], 0, 0, 0);
            __builtin_amdgcn_s_setprio(0);
        }
    };

    // ---- K-loop: minimum 2-phase recipe (T3+T4 box)
    const int nt = K >> 6;                   // 16
    STAGE(0);
    asm volatile("s_waitcnt vmcnt(0)" ::: "memory");
    __builtin_amdgcn_s_barrier();
    __builtin_amdgcn_sched_barrier(0);

    for (int t = 0; t < nt; ++t) {
        if (t + 1 < nt) {
            STAGE((t + 1) & 1);              // issue next-tile loads FIRST
            __builtin_amdgcn_sched_barrier(0);
        }
        COMPUTE(t & 1);                      // ds_read + MFMA on current tile
        if (t + 1 < nt) {
            asm volatile("s_waitcnt vmcnt(0)" ::: "memory");  // next tile landed
            __builtin_amdgcn_s_barrier();    // all waves done reading + staging
            __builtin_amdgcn_sched_barrier(0);
        }
    }

    // ---- epilogue: iso, store, fused row-sum (padded cols masked)
    const float dsv = fabsf(dsv_raw);
    #pragma unroll
    for (int m = 0; m < 8; ++m) {
        float rs0 = 0.f, rs1 = 0.f, rs2 = 0.f, rs3 = 0.f;
        const int row0 = brow + wr + m * 16 + kq * 4;   // C/D: row=(lane>>4)*4+j
        #pragma unroll
        for (int n = 0; n < 4; ++n) {
            const int col = bcol + wc + n * 16 + lr;    // col = lane&15
            const bool ok = col < C;
            float* op = out + (size_t)row0 * C + col;
            #pragma unroll
            for (int j = 0; j < 4; ++j) {
                const float sq  = fmaxf(2.f - 2.f * acc[m][n][j], 1e-12f);
                const float iso = dsv * (sqrtf(sq) * 0.70710678118654752f);
                if (ok) op[(size_t)j * C] = iso;
                const float c = ok ? iso : 0.f;
                if (j == 0) rs0 += c; else if (j == 1) rs1 += c;
                else if (j == 2) rs2 += c; else rs3 += c;
            }
        }
        float r4[4] = {rs0, rs1, rs2, rs3};
        #pragma unroll
        for (int j = 0; j < 4; ++j) {
            float r = r4[j];
            r += __shfl_xor(r, 1);
            r += __shfl_xor(r, 2);
            r += __shfl_xor(r, 4);
            r += __shfl_xor(r, 8);           // 16-lane group = full 64-col span
            if (lr == 0) atomicAdd(&rowsum[row0 + j], r);
        }
    }
}

// One block per row, pure streaming grid-stride within the row:
// logits = -(iso + rowsum/C) / T. 80 KB traffic per block.
__global__ __launch_bounds__(256) void finalize_kernel(
    float* __restrict__ out, const float* __restrict__ rowsum,
    const float* __restrict__ tptr, int C)
{
    const int row = blockIdx.x;
    const float mean = rowsum[row] / (float)C;
    const float invT = 1.f / tptr[0];
    float* rp = out + (size_t)row * C;
    const int n4 = C >> 2;                   // C % 4 == 0 (10000)
    for (int i = threadIdx.x; i < n4; i += 256) {
        float4 v = reinterpret_cast<const float4*>(rp)[i];
        v.x = -(v.x + mean) * invT;
        v.y = -(v.y + mean) * invT;
        v.z = -(v.z + mean) * invT;
        v.w = -(v.w + mean) * invT;
        reinterpret_cast<float4*>(rp)[i] = v;
    }
}

extern "C" void kernel_launch(void* const* d_in, const int* in_sizes, int n_in,
                              void* d_out, int out_size, void* d_ws, size_t ws_size,
                              hipStream_t stream)
{
    const float* feat = (const float*)d_in[0];
    const float* prot = (const float*)d_in[1];
    const float* dsc  = (const float*)d_in[2];
    const float* temp = (const float*)d_in[3];
    float* out = (float*)d_out;

    const int D = 1024;
    const int M = in_sizes[0] / D;            // 4096
    const int C = in_sizes[1] / D;            // 10000
    const int NT = (C + 255) / 256;           // 40
    const int Npad = NT * 256;                // 10240

    // ws: rowsum [M] f32 | features bf16 [M][D] | prototypes bf16 [Npad][D]
    float* rowsum = (float*)d_ws;
    unsigned short* fbf = (unsigned short*)(rowsum + M);
    unsigned short* pbf = fbf + (size_t)M * D;

    norm_rows_kernel<<<M, 256, 0, stream>>>(feat, fbf, M, rowsum);      // + zeroes rowsum
    norm_rows_kernel<<<Npad, 256, 0, stream>>>(prot, pbf, C, nullptr);
    gemm_iso_kernel<<<dim3(NT, M / 256), 512, 0, stream>>>(fbf, pbf, out, rowsum, dsc, M, C, D);
    finalize_kernel<<<M, 256, 0, stream>>>(out, rowsum, temp, C);
}

// Round 10
// 359.158 us; speedup vs baseline: 1.0769x; 1.0541x over previous
//
#include <hip/hip_runtime.h>
#include <hip/hip_bf16.h>

typedef __attribute__((ext_vector_type(8))) short short8;
typedef __attribute__((ext_vector_type(4))) float f32x4;

#define GLOBAL_AS __attribute__((address_space(1)))
#define LDS_AS    __attribute__((address_space(3)))

__device__ __forceinline__ void async_ld16(const void* g, void* l) {
    __builtin_amdgcn_global_load_lds((const GLOBAL_AS void*)g, (LDS_AS void*)l, 16, 0, 0);
}

__device__ __forceinline__ unsigned short f2bf(float x) {
    union { __hip_bfloat16 h; unsigned short u; } cv;
    cv.h = __float2bfloat16(x);
    return cv.u;
}

// One block per row (D=1024: 256 threads x float4). Rows >= rows_in write zeros.
// If rowsum != nullptr, thread 0 also zeroes rowsum[row] (fused zero init).
__global__ __launch_bounds__(256) void norm_rows_kernel(
    const float* __restrict__ in, unsigned short* __restrict__ outb, int rows_in,
    float* __restrict__ rowsum)
{
    const int row = blockIdx.x;
    const int tid = threadIdx.x;
    if (rowsum != nullptr && tid == 0) rowsum[row] = 0.f;
    float4 v = make_float4(0.f, 0.f, 0.f, 0.f);
    if (row < rows_in)
        v = reinterpret_cast<const float4*>(in + (size_t)row * 1024)[tid];
    float s = v.x * v.x + v.y * v.y + v.z * v.z + v.w * v.w;
    #pragma unroll
    for (int off = 32; off > 0; off >>= 1) s += __shfl_down(s, off);
    __shared__ float sr[4];
    if ((tid & 63) == 0) sr[tid >> 6] = s;
    __syncthreads();
    const float tot = sr[0] + sr[1] + sr[2] + sr[3];
    const float inv = 1.f / fmaxf(sqrtf(tot), 1e-12f);
    ushort4 o;
    o.x = f2bf(v.x * inv);
    o.y = f2bf(v.y * inv);
    o.z = f2bf(v.z * inv);
    o.w = f2bf(v.w * inv);
    reinterpret_cast<ushort4*>(outb + (size_t)row * 1024)[tid] = o;
}

// 256x128 tile (BM=256, BN=128), BK=64, 8 waves (4Mx2N), 16x16x32 bf16 MFMA,
// 4x4 frags/wave (64x64 per wave). LDS = ring of 3 x 48KB tile-buffers (144KB):
// STAGE(t+2) writes the slot consumed at t-1 (freed by t-1's barrier) -> true
// 2-deep prefetch; counted vmcnt(6) per tile (6 loads/tile/thread), never 0
// until the last tile (T3+T4). T2 source-side XOR swizzle + matching read XOR.
// T5 setprio around MFMA cluster. T1 bijective XCD swizzle (grid 1280 % 8 == 0,
// 5.0 blocks/CU exact -> no tail quantization).
// Epilogue: iso = |ds|*sqrt(max(2-2dot,eps))/sqrt2, store + per-row atomic sum.
__global__ __launch_bounds__(512, 2) void gemm_iso_kernel(
    const unsigned short* __restrict__ A,   // [M][1024] bf16 normalized features
    const unsigned short* __restrict__ B,   // [Npad][1024] bf16 normalized prototypes
    float* __restrict__ out,                // [M][C] iso
    float* __restrict__ rowsum,             // [M] zero-initialized
    const float* __restrict__ ds_ptr,
    int M, int C, int K)
{
    // ring slot s at lds + s*49152; within a slot: A 32KB (segs 0-31), B 16KB (segs 32-47)
    __shared__ __align__(16) char lds[3 * 49152];

    const float dsv_raw = ds_ptr[0];

    const int tid  = threadIdx.x;
    const int lane = tid & 63;
    const int wid  = tid >> 6;

    // T1: XCD-bijective swizzle (nwg = 1280, divisible by 8)
    const int orig = blockIdx.y * gridDim.x + blockIdx.x;
    const int cpx  = (gridDim.x * gridDim.y) >> 3;
    const int swz  = (orig & 7) * cpx + (orig >> 3);
    const int bx   = swz % gridDim.x;
    const int by   = swz / gridDim.x;
    const int brow = by * 256;
    const int bcol = bx * 128;

    // ---- staging: 48 segs of 1KB (8 rows x 128B); wave w owns segs 6w..6w+5
    const int lrow8 = lane >> 3;             // row within 8-row seg
    const int slotg = (lane & 7) ^ lrow8;    // pre-swizzled 16B slot (T2 write side)
    const size_t kb = (size_t)K * 2;

    const char* pG[6]; int lOff[6];
    #pragma unroll
    for (int i = 0; i < 6; ++i) {
        const int seg = wid * 6 + i;         // 0..47 (wave-uniform)
        if (seg < 32) {                      // A: rows 0..255
            const int r = seg * 8 + lrow8;
            pG[i] = (const char*)A + (size_t)(brow + r) * kb + slotg * 16;
        } else {                             // B: rows 0..127
            const int r = (seg - 32) * 8 + lrow8;
            pG[i] = (const char*)B + (size_t)(bcol + r) * kb + slotg * 16;
        }
        lOff[i] = seg * 1024;
    }

    auto STAGE = [&](int slot) {             // 6 loads/thread; advances ptrs by BK
        char* base = lds + slot * 49152;
        #pragma unroll
        for (int i = 0; i < 6; ++i) async_ld16(pG[i], base + lOff[i]);
        #pragma unroll
        for (int i = 0; i < 6; ++i) pG[i] += 128;
    };

    // ---- compute mapping: wave (wid>>1, wid&1) owns 64x64 of the 256x128 tile
    const int wr = (wid >> 1) * 64;
    const int wc = (wid & 1) * 64;
    const int lr = lane & 15;
    const int kq = lane >> 4;
    const int sx = lr & 7;                   // T2 read-side XOR (row&7 == lr&7)

    f32x4 acc[4][4];
    #pragma unroll
    for (int m = 0; m < 4; ++m)
        #pragma unroll
        for (int n = 0; n < 4; ++n)
            acc[m][n] = (f32x4){0.f, 0.f, 0.f, 0.f};

    int aoff[4], boff[4];
    #pragma unroll
    for (int m = 0; m < 4; ++m) aoff[m] = (wr + m * 16 + lr) * 128;
    #pragma unroll
    for (int n = 0; n < 4; ++n) boff[n] = 32768 + (wc + n * 16 + lr) * 128;
    const int so0 = ((0 + kq) ^ sx) * 16;    // kk=0 slots
    const int so1 = ((4 + kq) ^ sx) * 16;    // kk=1 slots

    auto COMPUTE = [&](int slot) {
        const char* base = lds + slot * 49152;
        #pragma unroll
        for (int kk = 0; kk < 2; ++kk) {
            const int so = kk ? so1 : so0;
            short8 a[4], b[4];
            #pragma unroll
            for (int m = 0; m < 4; ++m)
                a[m] = *reinterpret_cast<const short8*>(base + aoff[m] + so);
            #pragma unroll
            for (int n = 0; n < 4; ++n)
                b[n] = *reinterpret_cast<const short8*>(base + boff[n] + so);
            __builtin_amdgcn_s_setprio(1);
            #pragma unroll
            for (int m = 0; m < 4; ++m)
                #pragma unroll
                for (int n = 0; n < 4; ++n)
                    acc[m][n] = __builtin_amdgcn_mfma_f32_16x16x32_bf16(
                        a[m], b[n], acc[m][n], 0, 0, 0);
            __builtin_amdgcn_s_setprio(0);
        }
    };

    // ---- K-loop: 3-slot ring, 2-deep prefetch, counted vmcnt (T3+T4)
    const int nt = K >> 6;                   // 16
    int slot = 0;                            // slot of tile t; ring advances +1 mod 3
    STAGE(0);                                // tile 0 -> slot 0
    STAGE(1);                                // tile 1 -> slot 1   (12 in flight)
    asm volatile("s_waitcnt vmcnt(6)" ::: "memory");   // tile 0 landed
    __builtin_amdgcn_s_barrier();
    __builtin_amdgcn_sched_barrier(0);

    for (int t = 0; t < nt; ++t) {
        const bool more2 = (t + 2 < nt);
        if (more2) {
            // slot (slot+2)%3 held tile t-1: consumed, freed by iter t-1 barrier
            STAGE((slot + 2) % 3);
            __builtin_amdgcn_sched_barrier(0);
        }
        COMPUTE(slot);
        if (t + 1 < nt) {
            if (more2)
                asm volatile("s_waitcnt vmcnt(6)" ::: "memory");  // tile t+1 landed
            else
                asm volatile("s_waitcnt vmcnt(0)" ::: "memory");  // last tile
            __builtin_amdgcn_s_barrier();
            __builtin_amdgcn_sched_barrier(0);
        }
        slot = (slot + 1) % 3;
    }

    // ---- epilogue: iso, store, fused row-sum (padded cols masked)
    const float dsv = fabsf(dsv_raw);
    #pragma unroll
    for (int m = 0; m < 4; ++m) {
        float rs0 = 0.f, rs1 = 0.f, rs2 = 0.f, rs3 = 0.f;
        const int row0 = brow + wr + m * 16 + kq * 4;   // C/D: row=(lane>>4)*4+j
        #pragma unroll
        for (int n = 0; n < 4; ++n) {
            const int col = bcol + wc + n * 16 + lr;    // col = lane&15
            const bool ok = col < C;
            float* op = out + (size_t)row0 * C + col;
            #pragma unroll
            for (int j = 0; j < 4; ++j) {
                const float sq  = fmaxf(2.f - 2.f * acc[m][n][j], 1e-12f);
                const float iso = dsv * (sqrtf(sq) * 0.70710678118654752f);
                if (ok) op[(size_t)j * C] = iso;
                const float c = ok ? iso : 0.f;
                if (j == 0) rs0 += c; else if (j == 1) rs1 += c;
                else if (j == 2) rs2 += c; else rs3 += c;
            }
        }
        float r4[4] = {rs0, rs1, rs2, rs3};
        #pragma unroll
        for (int j = 0; j < 4; ++j) {
            float r = r4[j];
            r += __shfl_xor(r, 1);
            r += __shfl_xor(r, 2);
            r += __shfl_xor(r, 4);
            r += __shfl_xor(r, 8);           // 16-lane group = full 64-col span
            if (lr == 0) atomicAdd(&rowsum[row0 + j], r);
        }
    }
}

// One block per row, pure streaming grid-stride within the row:
// logits = -(iso + rowsum/C) / T.
__global__ __launch_bounds__(256) void finalize_kernel(
    float* __restrict__ out, const float* __restrict__ rowsum,
    const float* __restrict__ tptr, int C)
{
    const int row = blockIdx.x;
    const float mean = rowsum[row] / (float)C;
    const float invT = 1.f / tptr[0];
    float* rp = out + (size_t)row * C;
    const int n4 = C >> 2;                   // C % 4 == 0 (10000)
    for (int i = threadIdx.x; i < n4; i += 256) {
        float4 v = reinterpret_cast<const float4*>(rp)[i];
        v.x = -(v.x + mean) * invT;
        v.y = -(v.y + mean) * invT;
        v.z = -(v.z + mean) * invT;
        v.w = -(v.w + mean) * invT;
        reinterpret_cast<float4*>(rp)[i] = v;
    }
}

extern "C" void kernel_launch(void* const* d_in, const int* in_sizes, int n_in,
                              void* d_out, int out_size, void* d_ws, size_t ws_size,
                              hipStream_t stream)
{
    const float* feat = (const float*)d_in[0];
    const float* prot = (const float*)d_in[1];
    const float* dsc  = (const float*)d_in[2];
    const float* temp = (const float*)d_in[3];
    float* out = (float*)d_out;

    const int D = 1024;
    const int M = in_sizes[0] / D;            // 4096
    const int C = in_sizes[1] / D;            // 10000
    const int NT = (C + 127) / 128;           // 80
    const int Npad = NT * 128;                // 10240

    // ws: rowsum [M] f32 | features bf16 [M][D] | prototypes bf16 [Npad][D]
    float* rowsum = (float*)d_ws;
    unsigned short* fbf = (unsigned short*)(rowsum + M);
    unsigned short* pbf = fbf + (size_t)M * D;

    norm_rows_kernel<<<M, 256, 0, stream>>>(feat, fbf, M, rowsum);      // + zeroes rowsum
    norm_rows_kernel<<<Npad, 256, 0, stream>>>(prot, pbf, C, nullptr);
    gemm_iso_kernel<<<dim3(NT, M / 256), 512, 0, stream>>>(fbf, pbf, out, rowsum, dsc, M, C, D);
    finalize_kernel<<<M, 256, 0, stream>>>(out, rowsum, temp, C);
}